// Round 7
// baseline (520.460 us; speedup 1.0000x reference)
//
#include <hip/hip_runtime.h>
#include <hip/hip_bf16.h>

typedef __attribute__((ext_vector_type(8))) short bf16x8;
typedef _Float16 f16x8 __attribute__((ext_vector_type(8)));
typedef __attribute__((ext_vector_type(4))) float f32x4;

#define T_SEQ   512
#define B_BATCH 128
#define MB      64               // rows per block (4 waves x 16 rows)
#define ZSL_STRIDE 193           // f32 per row of per-wave z slice (192 + 1)
#define HS_STRIDE 68             // f32 per row of per-wave h slice (64 + 4)
#define LASTROW ((T_SEQ - 1) * B_BATCH)   // 65408

// ws layout (ushorts): 3 planes each: HF=fp16(f), HB=bf16(f), LB=bf16(f-fp16(f))
#define W0HF 0
#define W0HB 98304
#define W0LB 196608
#define W1HF 294912
#define W1HB 307200
#define W1LB 319488
// total 331776 ushorts = 663552 B of d_ws

// hybrid split: f ~= hf + (f-hf); cross terms via bf16. residual ~2^-19|f| [verified r6]
__device__ __forceinline__ void splitH(float f, unsigned& hf, unsigned& hb, unsigned& lb) {
    _Float16 h = (_Float16)f;
    hf = (unsigned)__builtin_bit_cast(unsigned short, h);
    float r = f - (float)h;
    hb = (unsigned)__builtin_bit_cast(unsigned short, __float2bfloat16(f));
    lb = (unsigned)__builtin_bit_cast(unsigned short, __float2bfloat16(r));
}

__device__ __forceinline__ void splitH8(const float* p, uint4& Pf, uint4& Pb, uint4& Pl) {
    float4 a = *(const float4*)p;
    float4 b = *(const float4*)(p + 4);
    float v[8] = {a.x, a.y, a.z, a.w, b.x, b.y, b.z, b.w};
    unsigned f[8], hb[8], lb[8];
#pragma unroll
    for (int i = 0; i < 8; ++i) splitH(v[i], f[i], hb[i], lb[i]);
    Pf = (uint4){f[0] | (f[1] << 16), f[2] | (f[3] << 16), f[4] | (f[5] << 16), f[6] | (f[7] << 16)};
    Pb = (uint4){hb[0] | (hb[1] << 16), hb[2] | (hb[3] << 16), hb[4] | (hb[5] << 16), hb[6] | (hb[7] << 16)};
    Pl = (uint4){lb[0] | (lb[1] << 16), lb[2] | (lb[3] << 16), lb[4] | (lb[5] << 16), lb[6] | (lb[7] << 16)};
}

// 3-product accumulate: hf*hf' (f16) + hb*lb' + lb*hb' (bf16)
__device__ __forceinline__ f32x4 mfma3(f16x8 af, bf16x8 ab, bf16x8 al,
                                       f16x8 bf, bf16x8 bb, bf16x8 bl, f32x4 c) {
    c = __builtin_amdgcn_mfma_f32_16x16x32_f16(af, bf, c, 0, 0, 0);
    c = __builtin_amdgcn_mfma_f32_16x16x32_bf16(ab, bl, c, 0, 0, 0);
    c = __builtin_amdgcn_mfma_f32_16x16x32_bf16(al, bb, c, 0, 0, 0);
    return c;
}

__device__ __forceinline__ float acc_sigmoid(float x) {
    float e = expf(-x);
    float d = 1.0f + e;
    float r = __builtin_amdgcn_rcpf(d);
    r = r * (2.0f - d * r);
    return r;
}

// inclusive prefix-product across the 64-lane wave [HW-verified r5/r6]
__device__ __forceinline__ float scan_prod(float v, int lane) {
    for (int d = 1; d < 64; d <<= 1) {
        float t = __shfl_up(v, d);
        v *= (lane >= d) ? t : 1.0f;
    }
    return v;
}

__device__ __forceinline__ float wave_sum(float v) {
    for (int d = 1; d < 64; d <<= 1) v += __shfl_xor(v, d);
    return v;
}

// ---------- kernel 1: pre-split weights into d_ws ----------
__global__ __launch_bounds__(256) void presplit_w(const float* __restrict__ W0,
                                                  const float* __restrict__ W1,
                                                  unsigned short* __restrict__ ws) {
    int i = blockIdx.x * 256 + threadIdx.x;
    if (i < 98304) {                      // W0 gates 1..3: flat rows 64..255, stride 576
        int r = i >> 9, k = i & 511;
        unsigned hf, hb, lb;
        splitH(W0[(r + 64) * 576 + k], hf, hb, lb);
        ws[W0HF + i] = (unsigned short)hf;
        ws[W0HB + i] = (unsigned short)hb;
        ws[W0LB + i] = (unsigned short)lb;
    } else if (i < 110592) {              // W1 gates 1..3: rows 64..255, stride 128, k<64
        int j = i - 98304;
        int r = j >> 6, k = j & 63;
        unsigned hf, hb, lb;
        splitH(W1[(r + 64) * 128 + k], hf, hb, lb);
        ws[W1HF + j] = (unsigned short)hf;
        ws[W1HB + j] = (unsigned short)hb;
        ws[W1LB + j] = (unsigned short)lb;
    }
}

// ---------- kernel 2: fused QLSTM, zero __syncthreads ----------
// Each wave owns 16 rows end-to-end. All LDS wave-private:
//   [0, 12352)       zsl: 4 waves x [4][193] f32  (z redistribution slice)
//   [12352, 29760)   hsl: 4 waves x [16][68] f32  (layer-0 LN output)
__global__ __launch_bounds__(256, 4) void qlstm_fused(
    const float* __restrict__ x,
    const float* __restrict__ b0,
    const float* __restrict__ th0,
    const float* __restrict__ g0,
    const float* __restrict__ be0,
    const float* __restrict__ b1,
    const float* __restrict__ th1,
    const float* __restrict__ g1,
    const float* __restrict__ be1,
    const unsigned short* __restrict__ wsp,
    float* __restrict__ out)
{
    __shared__ __align__(16) char lds[29760];

    const int tid  = threadIdx.x;
    const int lane = tid & 63;
    const int wave = tid >> 6;
    const int ln   = lane & 15;   // MFMA m/n lane index
    const int quad = lane >> 4;   // MFMA k-group / D-row group

    float* zsl = (float*)lds + wave * (4 * ZSL_STRIDE);            // [4][193]
    float* hsl = (float*)(lds + 12352) + wave * (16 * HS_STRIDE);  // [16][68]

    const long rowbase = (long)blockIdx.x * MB + wave * 16;   // wave's first (t*B+b) row

    float* out0 = out;                                      // h1      [T*B][64]
    float* out1 = out + (long)T_SEQ * B_BATCH * 64;         // h0[-1]  [128][64]
    float* out2 = out1 + B_BATCH * 64;                      // c0[-1]
    float* out3 = out2 + B_BATCH * 64;                      // h1[-1]
    float* out4 = out3 + B_BATCH * 64;                      // c1[-1]

    // per-lane constants: lane == qubit index in the fused phase
    const float bt0a = b0[64  + lane] + th0[64  + lane];
    const float bt0b = b0[128 + lane] + th0[128 + lane];
    const float bt0c = b0[192 + lane] + th0[192 + lane];
    const float bt1a = b1[64  + lane] + th1[64  + lane];
    const float bt1b = b1[128 + lane] + th1[128 + lane];
    const float bt1c = b1[192 + lane] + th1[192 + lane];
    const float g0v = g0[lane], be0v = be0[lane];
    const float g1v = g1[lane], be1v = be1[lane];

    // ------- GEMM1: z0[16][192] = x[16][512] . W0g^T  (A direct from global, no LDS)
    f32x4 acc[12];
#pragma unroll
    for (int nt = 0; nt < 12; ++nt) acc[nt] = (f32x4){0.f, 0.f, 0.f, 0.f};

    const float* xr = x + (rowbase + ln) * 512 + quad * 8;   // this lane's A stream
    for (int kc = 0; kc < 512; kc += 32) {
        uint4 Pf, Pb, Pl;
        splitH8(xr + kc, Pf, Pb, Pl);
        f16x8  Af = __builtin_bit_cast(f16x8, Pf);
        bf16x8 Ab = __builtin_bit_cast(bf16x8, Pb);
        bf16x8 Al = __builtin_bit_cast(bf16x8, Pl);
        int kb = kc + quad * 8;
#pragma unroll
        for (int nt = 0; nt < 12; ++nt) {
            int bo = (nt * 16 + ln) * 512 + kb;
            f16x8  Bf = *(const f16x8*)(wsp + W0HF + bo);
            bf16x8 Bb = *(const bf16x8*)(wsp + W0HB + bo);
            bf16x8 Bl = *(const bf16x8*)(wsp + W0LB + bo);
            acc[nt] = mfma3(Af, Ab, Al, Bf, Bb, Bl, acc[nt]);
        }
    }

    // ------- layer 0: per-quad redistribution + fused cumprod/gates/LN (no barriers)
    for (int g2 = 0; g2 < 4; ++g2) {
        if (quad == g2) {      // D rows g2*4+i live in quad g2: write them to the slice
#pragma unroll
            for (int nt = 0; nt < 12; ++nt)
#pragma unroll
                for (int i = 0; i < 4; ++i)
                    zsl[i * ZSL_STRIDE + nt * 16 + ln] = acc[nt][i];
        }
        asm volatile("s_waitcnt lgkmcnt(0)" ::: "memory");   // intra-wave LDS ordering
#pragma unroll
        for (int p = 0; p < 4; ++p) {
            const float* zr = zsl + p * ZSL_STRIDE;
            float c1 = cosf(zr[lane]       + bt0a);
            float c2 = cosf(zr[64 + lane]  + bt0b);
            float c3 = cosf(zr[128 + lane] + bt0c);
            float q1 = scan_prod(c1, lane);
            float q2 = scan_prod(c2, lane);
            float q3 = scan_prod(c3, lane);
            float ig = acc_sigmoid(q1);
            float gg = tanhf(acc_sigmoid(q2));
            float og = acc_sigmoid(q3);
            float c  = ig * gg;
            float hv = og * tanhf(c);
            float mu = wave_sum(hv) * (1.0f / 64.0f);
            float d  = hv - mu;
            float var = wave_sum(d * d) * (1.0f / 64.0f);
            float rs  = rsqrtf(var + 1e-5f);
            float hl  = d * rs * g0v + be0v;
            int row = g2 * 4 + p;
            hsl[row * HS_STRIDE + lane] = hl;
            long tbrow = rowbase + row;
            if (tbrow >= LASTROW) {
                int bidx = (int)(tbrow - LASTROW);
                out1[bidx * 64 + lane] = hl;
                out2[bidx * 64 + lane] = c;
            }
        }
    }
    asm volatile("s_waitcnt lgkmcnt(0)" ::: "memory");

    // ------- GEMM2: z1[16][192] = h0[16][64] . W1g^T  (A from wave-private hsl)
    f32x4 acc2[12];
#pragma unroll
    for (int nt = 0; nt < 12; ++nt) acc2[nt] = (f32x4){0.f, 0.f, 0.f, 0.f};
    for (int k0 = 0; k0 < 64; k0 += 32) {
        int ka = k0 + quad * 8;
        uint4 Pf, Pb, Pl;
        splitH8(hsl + ln * HS_STRIDE + ka, Pf, Pb, Pl);
        f16x8  Af = __builtin_bit_cast(f16x8, Pf);
        bf16x8 Ab = __builtin_bit_cast(bf16x8, Pb);
        bf16x8 Al = __builtin_bit_cast(bf16x8, Pl);
#pragma unroll
        for (int nt = 0; nt < 12; ++nt) {
            int bo = (nt * 16 + ln) * 64 + ka;
            f16x8  Bf = *(const f16x8*)(wsp + W1HF + bo);
            bf16x8 Bb = *(const bf16x8*)(wsp + W1HB + bo);
            bf16x8 Bl = *(const bf16x8*)(wsp + W1LB + bo);
            acc2[nt] = mfma3(Af, Ab, Al, Bf, Bb, Bl, acc2[nt]);
        }
    }

    // ------- layer 1: redistribution + fused phase -> outputs (no barriers)
    for (int g2 = 0; g2 < 4; ++g2) {
        if (quad == g2) {
#pragma unroll
            for (int nt = 0; nt < 12; ++nt)
#pragma unroll
                for (int i = 0; i < 4; ++i)
                    zsl[i * ZSL_STRIDE + nt * 16 + ln] = acc2[nt][i];
        }
        asm volatile("s_waitcnt lgkmcnt(0)" ::: "memory");
#pragma unroll
        for (int p = 0; p < 4; ++p) {
            const float* zr = zsl + p * ZSL_STRIDE;
            float c1 = cosf(zr[lane]       + bt1a);
            float c2 = cosf(zr[64 + lane]  + bt1b);
            float c3 = cosf(zr[128 + lane] + bt1c);
            float q1 = scan_prod(c1, lane);
            float q2 = scan_prod(c2, lane);
            float q3 = scan_prod(c3, lane);
            float ig = acc_sigmoid(q1);
            float gg = tanhf(acc_sigmoid(q2));
            float og = acc_sigmoid(q3);
            float c  = ig * gg;
            float hv = og * tanhf(c);
            float mu = wave_sum(hv) * (1.0f / 64.0f);
            float d  = hv - mu;
            float var = wave_sum(d * d) * (1.0f / 64.0f);
            float rs  = rsqrtf(var + 1e-5f);
            float hl  = d * rs * g1v + be1v;
            int row = g2 * 4 + p;
            long tbrow = rowbase + row;
            out0[tbrow * 64 + lane] = hl;
            if (tbrow >= LASTROW) {
                int bidx = (int)(tbrow - LASTROW);
                out3[bidx * 64 + lane] = hl;
                out4[bidx * 64 + lane] = c;
            }
        }
    }
}

extern "C" void kernel_launch(void* const* d_in, const int* in_sizes, int n_in,
                              void* d_out, int out_size, void* d_ws, size_t ws_size,
                              hipStream_t stream) {
    const float* x   = (const float*)d_in[0];
    const float* W0  = (const float*)d_in[1];
    const float* b0  = (const float*)d_in[2];
    const float* th0 = (const float*)d_in[3];
    const float* g0  = (const float*)d_in[4];
    const float* be0 = (const float*)d_in[5];
    const float* W1  = (const float*)d_in[6];
    const float* b1  = (const float*)d_in[7];
    const float* th1 = (const float*)d_in[8];
    const float* g1  = (const float*)d_in[9];
    const float* be1 = (const float*)d_in[10];
    unsigned short* wsp = (unsigned short*)d_ws;   // needs 663552 B

    presplit_w<<<dim3(432), dim3(256), 0, stream>>>(W0, W1, wsp);
    qlstm_fused<<<dim3(1024), dim3(256), 0, stream>>>(
        x, b0, th0, g0, be0, b1, th1, g1, be1, wsp, (float*)d_out);
}